// Round 1
// baseline (600.393 us; speedup 1.0000x reference)
//
#include <hip/hip_runtime.h>
#include <hip/hip_bf16.h>
#include <stdint.h>

#define N_  6144
#define T_  3072
#define D_  128
#define H_  4
#define HD_ 512

typedef float f32x4 __attribute__((ext_vector_type(4)));
typedef short s16x8 __attribute__((ext_vector_type(8)));

static __device__ __forceinline__ short f2bf(float f) {
  union { __hip_bfloat16 b; short s; } u;
  u.b = __float2bfloat16(f);
  return u.s;
}

// ---------------- adj (int32 0/1) -> bitmask ----------------
__global__ __launch_bounds__(256) void bits_kernel(const int* __restrict__ adj,
                                                   unsigned long long* __restrict__ bits,
                                                   int nwords) {
  int lane = threadIdx.x & 63;
  int gw = (blockIdx.x * blockDim.x + threadIdx.x) >> 6;
  int nw = (gridDim.x * blockDim.x) >> 6;
  for (int w = gw; w < nwords; w += nw) {
    int v = adj[(long)w * 64 + lane];
    unsigned long long b = __ballot(v != 0);
    if (lane == 0) bits[w] = b;
  }
}

// ---------------- fp32 -> bf16 (same layout) ----------------
__global__ __launch_bounds__(256) void cvt_kernel(const float* __restrict__ in,
                                                  short* __restrict__ out, int count4) {
  int i = blockIdx.x * blockDim.x + threadIdx.x;
  if (i < count4) {
    float4 v = *(const float4*)(in + (long)i * 4);
    short4 o;
    o.x = f2bf(v.x); o.y = f2bf(v.y); o.z = f2bf(v.z); o.w = f2bf(v.w);
    *(short4*)(out + (long)i * 4) = o;
  }
}

// ---------------- fp32 [R][C] -> bf16 [C][R] (batched) ----------------
__global__ __launch_bounds__(256) void tcvt_kernel(const float* __restrict__ in,
                                                   short* __restrict__ out,
                                                   int R, int C, long sIn, long sOut) {
  __shared__ float t[32][33];
  in += (long)blockIdx.z * sIn;
  out += (long)blockIdx.z * sOut;
  int c0 = blockIdx.x * 32, r0 = blockIdx.y * 32;
  int tx = threadIdx.x, ty = threadIdx.y;   // block (32,8)
#pragma unroll
  for (int i = 0; i < 4; ++i)
    t[ty + 8 * i][tx] = in[(long)(r0 + ty + 8 * i) * C + c0 + tx];
  __syncthreads();
#pragma unroll
  for (int i = 0; i < 4; ++i)
    out[(long)(c0 + ty + 8 * i) * R + r0 + tx] = f2bf(t[tx][ty + 8 * i]);
}

// ---------------- u_s[h][d] = sum_e W[h][d][e]*a_src[h][e] ----------------
__global__ void headvec_kernel(const float* __restrict__ W, const float* __restrict__ a_s,
                               const float* __restrict__ a_d, float* __restrict__ u_s,
                               float* __restrict__ u_d) {
  int h = blockIdx.x, d = threadIdx.x;
  const float* wr = W + ((long)h * D_ + d) * D_;
  const float* as = a_s + h * D_;
  const float* ad = a_d + h * D_;
  float s = 0.f, t = 0.f;
#pragma unroll 8
  for (int e = 0; e < D_; ++e) { s += wr[e] * as[e]; t += wr[e] * ad[e]; }
  u_s[h * D_ + d] = s;
  u_d[h * D_ + d] = t;
}

// ---------------- f_s/f_d (pre-scaled by log2e and 0.2*log2e) ----------------
__global__ __launch_bounds__(256) void fvec_kernel(const float* __restrict__ x,
                                                   const float* __restrict__ u_s,
                                                   const float* __restrict__ u_d,
                                                   float* __restrict__ fsA, float* __restrict__ fsB,
                                                   float* __restrict__ fdA, float* __restrict__ fdB,
                                                   int n) {
  long idx = (long)blockIdx.x * 256 + threadIdx.x;
  int h = (int)(idx / n), i = (int)(idx % n);
  const float* xr = x + (long)i * D_;
  const float* us = u_s + h * D_;
  const float* ud = u_d + h * D_;
  float s = 0.f, t = 0.f;
#pragma unroll 8
  for (int e = 0; e < D_; ++e) { s += xr[e] * us[e]; t += xr[e] * ud[e]; }
  const float L2E = 1.4426950408889634f;
  fsA[idx] = s * L2E; fsB[idx] = 0.2f * s * L2E;
  fdA[idx] = t * L2E; fdB[idx] = 0.2f * t * L2E;
}

// ---------------- generic bf16 MFMA GEMM: C[M][128cols] = A[M][K] * BT[ncol][K]^T ----
// block: 256 thr (4 waves), tile 64 rows x 128 cols, K in steps of 32.
// epi: 0 = bf16 store (WhT), 1 = fp32 relu+bias, 2 = bf16 relu+bias transposed store, 3 = fp32 plain
__global__ __launch_bounds__(256) void gemm_kernel(const short* __restrict__ A,
                                                   const short* __restrict__ BT,
                                                   int M, int K, int lda, int ldb,
                                                   float* __restrict__ outF, short* __restrict__ outB,
                                                   const float* __restrict__ bias,
                                                   int ldo, int epi,
                                                   long sA, long sBT, long sOut) {
  int bz = blockIdx.z;
  A += bz * sA;
  BT += bz * sBT;
  __shared__ __align__(16) short bs[4096];  // 8KB, fragment-ordered
  int tid = threadIdx.x, w = tid >> 6, l = tid & 63, lm = l & 15, lg = l >> 4;
  int row0 = blockIdx.x * 64 + w * 16;
  int col0 = blockIdx.y * 128;
  const short* arow = A + (long)(row0 + lm) * lda + 8 * lg;
  const short* b0 = BT + (long)(col0 + 16 * (2 * w + 0) + lm) * ldb + 8 * lg;
  const short* b1 = BT + (long)(col0 + 16 * (2 * w + 1) + lm) * ldb + 8 * lg;
  f32x4 acc[8] = {};
  int nt = K / 32;
  for (int kt = 0; kt < nt; ++kt) {
    int kb = kt * 32;
    int4 r0 = *(const int4*)(b0 + kb);
    int4 r1 = *(const int4*)(b1 + kb);
    s16x8 af = *(const s16x8*)(arow + kb);
    __syncthreads();
    ((int4*)bs)[(2 * w + 0) * 64 + l] = r0;
    ((int4*)bs)[(2 * w + 1) * 64 + l] = r1;
    __syncthreads();
#pragma unroll
    for (int f = 0; f < 8; ++f) {
      s16x8 bf = *(const s16x8*)(bs + f * 512 + l * 8);
      acc[f] = __builtin_amdgcn_mfma_f32_16x16x32_bf16(af, bf, acc[f], 0, 0, 0);
    }
  }
#pragma unroll
  for (int f = 0; f < 8; ++f) {
    int col = col0 + 16 * f + lm;
#pragma unroll
    for (int r = 0; r < 4; ++r) {
      int row = row0 + 4 * lg + r;
      float v = acc[f][r];
      if (epi == 0) {
        outB[bz * sOut + (long)row * ldo + col] = f2bf(v);
      } else if (epi == 1) {
        v += bias[col]; v = v > 0.f ? v : 0.f;
        outF[(long)row * ldo + col] = v;
      } else if (epi == 2) {
        v += bias[col]; v = v > 0.f ? v : 0.f;
        outB[(long)col * ldo + row] = f2bf(v);
      } else {
        outF[(long)row * ldo + col] = v;
      }
    }
  }
}

// ---------------- fused masked-softmax attention + elu, per head ----------------
// grid (n/64, H), block 256. Out: hcat bf16 [n][512] (head-concat).
__global__ __launch_bounds__(256) void attn_kernel(const short* __restrict__ WhT,
                                                   const unsigned char* __restrict__ bits,
                                                   const float* __restrict__ fsA,
                                                   const float* __restrict__ fsB,
                                                   const float* __restrict__ fdA,
                                                   const float* __restrict__ fdB,
                                                   short* __restrict__ hcat, int n) {
  int h = blockIdx.y;
  const short* whT = WhT + (long)h * D_ * n;
  const float* fa = fdA + (long)h * n;
  const float* fb = fdB + (long)h * n;
  __shared__ __align__(16) short bs[4096];
  __shared__ float zlds[64];
  int tid = threadIdx.x, w = tid >> 6, l = tid & 63, lm = l & 15, lg = l >> 4;
  int i0 = blockIdx.x * 64 + w * 16;
  int irow = i0 + lm;
  float fsAi = fsA[(long)h * n + irow];
  float fsBi = fsB[(long)h * n + irow];
  const unsigned char* brow = bits + (long)irow * (n >> 3);
  const short* s0 = whT + (long)(16 * (2 * w + 0) + lm) * n + 8 * lg;
  const short* s1 = whT + (long)(16 * (2 * w + 1) + lm) * n + 8 * lg;
  f32x4 acc[8] = {};
  float zacc = 0.f;
  int nt = n / 32;
  for (int kt = 0; kt < nt; ++kt) {
    int jb = kt * 32;
    int4 r0 = *(const int4*)(s0 + jb);
    int4 r1 = *(const int4*)(s1 + jb);
    // P fragment (A operand): rows lm, k = jb + 8*lg + j
    float fav[8], fbv[8];
    *(float4*)(fav) = *(const float4*)(fa + jb + 8 * lg);
    *(float4*)(fav + 4) = *(const float4*)(fa + jb + 8 * lg + 4);
    *(float4*)(fbv) = *(const float4*)(fb + jb + 8 * lg);
    *(float4*)(fbv + 4) = *(const float4*)(fb + jb + 8 * lg + 4);
    unsigned mb = brow[(jb + 8 * lg) >> 3];
    s16x8 af;
    float zs = 0.f;
#pragma unroll
    for (int j = 0; j < 8; ++j) {
      float p = exp2f(fmaxf(fsAi + fav[j], fsBi + fbv[j]));
      p = ((mb >> j) & 1u) ? p : 0.f;
      zs += p;
      af[j] = f2bf(p);
    }
    zacc += zs;
    __syncthreads();
    ((int4*)bs)[(2 * w + 0) * 64 + l] = r0;
    ((int4*)bs)[(2 * w + 1) * 64 + l] = r1;
    __syncthreads();
#pragma unroll
    for (int f = 0; f < 8; ++f) {
      s16x8 bf = *(const s16x8*)(bs + f * 512 + l * 8);
      acc[f] = __builtin_amdgcn_mfma_f32_16x16x32_bf16(af, bf, acc[f], 0, 0, 0);
    }
  }
  // reduce Z across the 4 k-groups (lanes sharing lm)
  zacc += __shfl_xor(zacc, 16);
  zacc += __shfl_xor(zacc, 32);
  zlds[w * 16 + lm] = zacc;
  __syncthreads();
  float invz[4];
#pragma unroll
  for (int r = 0; r < 4; ++r) invz[r] = 1.f / zlds[w * 16 + 4 * lg + r];
#pragma unroll
  for (int f = 0; f < 8; ++f) {
#pragma unroll
    for (int r = 0; r < 4; ++r) {
      float v = acc[f][r] * invz[r];
      v = v > 0.f ? v : (__expf(v) - 1.f);  // elu
      hcat[(long)(i0 + 4 * lg + r) * HD_ + h * D_ + 16 * f + lm] = f2bf(v);
    }
  }
}

// ---------------- gated fusion + final GEMM + relu ----------------
__global__ __launch_bounds__(256) void fusion_kernel(const float* __restrict__ concept,
                                                     const float* __restrict__ ctext,
                                                     const short* __restrict__ fusT,
                                                     const float* __restrict__ fus_b,
                                                     float* __restrict__ out) {
  __shared__ __align__(16) short als[64 * 136];  // row pitch 136 shorts (272B) to dodge conflicts
  int tid = threadIdx.x;
  int r0 = blockIdx.x * 64;
#pragma unroll
  for (int it = 0; it < 8; ++it) {
    int e = it * 1024 + tid * 4;
    int r = e >> 7, c = e & 127;
    float4 cv = *(const float4*)(concept + (long)(r0 + r) * D_ + c);
    float4 tv = *(const float4*)(ctext + (long)(r0 + r) * D_ + c);
    short4 o;
    {
      float s = cv.x + tv.x; float z = 1.f / (1.f + __expf(-s)); o.x = f2bf(tv.x + z * (cv.x - tv.x));
      s = cv.y + tv.y; z = 1.f / (1.f + __expf(-s)); o.y = f2bf(tv.y + z * (cv.y - tv.y));
      s = cv.z + tv.z; z = 1.f / (1.f + __expf(-s)); o.z = f2bf(tv.z + z * (cv.z - tv.z));
      s = cv.w + tv.w; z = 1.f / (1.f + __expf(-s)); o.w = f2bf(tv.w + z * (cv.w - tv.w));
    }
    *(short4*)(als + (long)r * 136 + c) = o;
  }
  __syncthreads();
  int w = tid >> 6, l = tid & 63, lm = l & 15, lg = l >> 4;
  f32x4 acc[8] = {};
#pragma unroll
  for (int kt = 0; kt < 4; ++kt) {
    int kb = kt * 32;
    s16x8 af = *(const s16x8*)(als + (16 * w + lm) * 136 + kb + 8 * lg);
#pragma unroll
    for (int f = 0; f < 8; ++f) {
      s16x8 bf = *(const s16x8*)(fusT + (long)(16 * f + lm) * D_ + kb + 8 * lg);
      acc[f] = __builtin_amdgcn_mfma_f32_16x16x32_bf16(af, bf, acc[f], 0, 0, 0);
    }
  }
#pragma unroll
  for (int f = 0; f < 8; ++f) {
    int col = 16 * f + lm;
#pragma unroll
    for (int r = 0; r < 4; ++r) {
      float v = acc[f][r] + fus_b[col];
      v = v > 0.f ? v : 0.f;
      out[(long)(r0 + 16 * w + 4 * lg + r) * D_ + col] = v;
    }
  }
}

extern "C" void kernel_launch(void* const* d_in, const int* in_sizes, int n_in,
                              void* d_out, int out_size, void* d_ws, size_t ws_size,
                              hipStream_t stream) {
  (void)in_sizes; (void)n_in; (void)out_size; (void)ws_size;
  const float* x      = (const float*)d_in[0];
  const int*   adj    = (const int*)d_in[1];
  const float* t_x    = (const float*)d_in[2];
  const int*   t_adj  = (const int*)d_in[3];
  const float* tfidf  = (const float*)d_in[4];
  const float* Wg     = (const float*)d_in[5];
  const float* ag_src = (const float*)d_in[6];
  const float* ag_dst = (const float*)d_in[7];
  const float* fcg_W  = (const float*)d_in[8];
  const float* fcg_b  = (const float*)d_in[9];
  const float* Wt     = (const float*)d_in[10];
  const float* at_src = (const float*)d_in[11];
  const float* at_dst = (const float*)d_in[12];
  const float* fct_W  = (const float*)d_in[13];
  const float* fct_b  = (const float*)d_in[14];
  const float* fus_W  = (const float*)d_in[15];
  const float* fus_b  = (const float*)d_in[16];
  float* out = (float*)d_out;

  char* ws = (char*)d_ws;
  size_t off = 0;
  auto alloc = [&](size_t bytes) -> char* {
    char* p = ws + off;
    off = (off + bytes + 255) & ~(size_t)255;
    return p;
  };
  unsigned long long* bitsG = (unsigned long long*)alloc((size_t)N_ * N_ / 8);
  unsigned long long* bitsT = (unsigned long long*)alloc((size_t)T_ * T_ / 8);
  short* xb     = (short*)alloc((size_t)N_ * D_ * 2);
  short* txb    = (short*)alloc((size_t)T_ * D_ * 2);
  short* WgT    = (short*)alloc((size_t)H_ * D_ * D_ * 2);
  short* WtT    = (short*)alloc((size_t)H_ * D_ * D_ * 2);
  short* fcgT   = (short*)alloc((size_t)HD_ * D_ * 2);
  short* fctT   = (short*)alloc((size_t)HD_ * D_ * 2);
  short* fusT   = (short*)alloc((size_t)D_ * D_ * 2);
  short* tfidfT = (short*)alloc((size_t)N_ * T_ * 2);
  short* WhTg   = (short*)alloc((size_t)H_ * D_ * N_ * 2);
  short* WhTt   = (short*)alloc((size_t)H_ * D_ * T_ * 2);
  float* usG = (float*)alloc(H_ * D_ * 4);
  float* udG = (float*)alloc(H_ * D_ * 4);
  float* usT = (float*)alloc(H_ * D_ * 4);
  float* udT = (float*)alloc(H_ * D_ * 4);
  float* fsAg = (float*)alloc((size_t)H_ * N_ * 4);
  float* fsBg = (float*)alloc((size_t)H_ * N_ * 4);
  float* fdAg = (float*)alloc((size_t)H_ * N_ * 4);
  float* fdBg = (float*)alloc((size_t)H_ * N_ * 4);
  float* fsAt = (float*)alloc((size_t)H_ * T_ * 4);
  float* fsBt = (float*)alloc((size_t)H_ * T_ * 4);
  float* fdAt = (float*)alloc((size_t)H_ * T_ * 4);
  float* fdBt = (float*)alloc((size_t)H_ * T_ * 4);
  short* hcatG = (short*)alloc((size_t)N_ * HD_ * 2);
  short* hcatT = (short*)alloc((size_t)T_ * HD_ * 2);
  short* gatT  = (short*)alloc((size_t)D_ * T_ * 2);
  float* conceptF = (float*)alloc((size_t)N_ * D_ * 4);
  float* ctextF   = (float*)alloc((size_t)N_ * D_ * 4);

  // --- prep ---
  bits_kernel<<<dim3(1024), dim3(256), 0, stream>>>(adj, bitsG, N_ * N_ / 64);
  bits_kernel<<<dim3(512), dim3(256), 0, stream>>>(t_adj, bitsT, T_ * T_ / 64);
  cvt_kernel<<<dim3(N_ * D_ / 1024), dim3(256), 0, stream>>>(x, xb, N_ * D_ / 4);
  cvt_kernel<<<dim3(T_ * D_ / 1024), dim3(256), 0, stream>>>(t_x, txb, T_ * D_ / 4);
  tcvt_kernel<<<dim3(4, 4, 4), dim3(32, 8), 0, stream>>>(Wg, WgT, D_, D_, (long)D_ * D_, (long)D_ * D_);
  tcvt_kernel<<<dim3(4, 4, 4), dim3(32, 8), 0, stream>>>(Wt, WtT, D_, D_, (long)D_ * D_, (long)D_ * D_);
  tcvt_kernel<<<dim3(4, 16, 1), dim3(32, 8), 0, stream>>>(fcg_W, fcgT, HD_, D_, 0, 0);
  tcvt_kernel<<<dim3(4, 16, 1), dim3(32, 8), 0, stream>>>(fct_W, fctT, HD_, D_, 0, 0);
  tcvt_kernel<<<dim3(4, 4, 1), dim3(32, 8), 0, stream>>>(fus_W, fusT, D_, D_, 0, 0);
  tcvt_kernel<<<dim3(N_ / 32, T_ / 32, 1), dim3(32, 8), 0, stream>>>(tfidf, tfidfT, T_, N_, 0, 0);
  headvec_kernel<<<dim3(H_), dim3(128), 0, stream>>>(Wg, ag_src, ag_dst, usG, udG);
  headvec_kernel<<<dim3(H_), dim3(128), 0, stream>>>(Wt, at_src, at_dst, usT, udT);
  fvec_kernel<<<dim3(H_ * N_ / 256), dim3(256), 0, stream>>>(x, usG, udG, fsAg, fsBg, fdAg, fdBg, N_);
  fvec_kernel<<<dim3(H_ * T_ / 256), dim3(256), 0, stream>>>(t_x, usT, udT, fsAt, fsBt, fdAt, fdBt, T_);

  // --- WhT = W^T x^T  (per head), bf16 out [H][128][n] ---
  gemm_kernel<<<dim3(2, N_ / 128, H_), dim3(256), 0, stream>>>(
      WgT, xb, D_, D_, D_, D_, nullptr, WhTg, nullptr, N_, 0,
      (long)D_ * D_, 0, (long)D_ * N_);
  gemm_kernel<<<dim3(2, T_ / 128, H_), dim3(256), 0, stream>>>(
      WtT, txb, D_, D_, D_, D_, nullptr, WhTt, nullptr, T_, 0,
      (long)D_ * D_, 0, (long)D_ * T_);

  // --- attention ---
  attn_kernel<<<dim3(N_ / 64, H_), dim3(256), 0, stream>>>(
      WhTg, (const unsigned char*)bitsG, fsAg, fsBg, fdAg, fdBg, hcatG, N_);
  attn_kernel<<<dim3(T_ / 64, H_), dim3(256), 0, stream>>>(
      WhTt, (const unsigned char*)bitsT, fsAt, fsBt, fdAt, fdBt, hcatT, T_);

  // --- head-concat FC: concept (fp32) and gat_text (bf16, transposed) ---
  gemm_kernel<<<dim3(N_ / 64, 1, 1), dim3(256), 0, stream>>>(
      hcatG, fcgT, N_, HD_, HD_, HD_, conceptF, nullptr, fcg_b, D_, 1, 0, 0, 0);
  gemm_kernel<<<dim3(T_ / 64, 1, 1), dim3(256), 0, stream>>>(
      hcatT, fctT, T_, HD_, HD_, HD_, nullptr, gatT, fct_b, T_, 2, 0, 0, 0);

  // --- c_text = tfidf^T @ gat_text ---
  gemm_kernel<<<dim3(N_ / 64, 1, 1), dim3(256), 0, stream>>>(
      tfidfT, gatT, N_, T_, T_, T_, ctextF, nullptr, nullptr, D_, 3, 0, 0, 0);

  // --- gated fusion + final linear + relu ---
  fusion_kernel<<<dim3(N_ / 64), dim3(256), 0, stream>>>(conceptF, ctextF, fusT, fus_b, out);
}

// Round 2
// 506.582 us; speedup vs baseline: 1.1852x; 1.1852x over previous
//
#include <hip/hip_runtime.h>
#include <hip/hip_bf16.h>
#include <stdint.h>

#define N_  6144
#define T_  3072
#define D_  128
#define H_  4
#define HD_ 512

typedef float f32x4 __attribute__((ext_vector_type(4)));
typedef short s16x8 __attribute__((ext_vector_type(8)));

static __device__ __forceinline__ short f2bf(float f) {
  union { __hip_bfloat16 b; short s; } u;
  u.b = __float2bfloat16(f);
  return u.s;
}

// ---------------- adj (int32 0/1) -> bitmask ----------------
__global__ __launch_bounds__(256) void bits_kernel(const int* __restrict__ adj,
                                                   unsigned long long* __restrict__ bits,
                                                   int nwords) {
  int lane = threadIdx.x & 63;
  int gw = (blockIdx.x * blockDim.x + threadIdx.x) >> 6;
  int nw = (gridDim.x * blockDim.x) >> 6;
  for (int w = gw; w < nwords; w += nw) {
    int v = adj[(long)w * 64 + lane];
    unsigned long long b = __ballot(v != 0);
    if (lane == 0) bits[w] = b;
  }
}

// ---------------- fp32 -> bf16 (same layout) ----------------
__global__ __launch_bounds__(256) void cvt_kernel(const float* __restrict__ in,
                                                  short* __restrict__ out, int count4) {
  int i = blockIdx.x * blockDim.x + threadIdx.x;
  if (i < count4) {
    float4 v = *(const float4*)(in + (long)i * 4);
    short4 o;
    o.x = f2bf(v.x); o.y = f2bf(v.y); o.z = f2bf(v.z); o.w = f2bf(v.w);
    *(short4*)(out + (long)i * 4) = o;
  }
}

// ---------------- fp32 [R][C] -> bf16 [C][R] (batched) ----------------
__global__ __launch_bounds__(256) void tcvt_kernel(const float* __restrict__ in,
                                                   short* __restrict__ out,
                                                   int R, int C, long sIn, long sOut) {
  __shared__ float t[32][33];
  in += (long)blockIdx.z * sIn;
  out += (long)blockIdx.z * sOut;
  int c0 = blockIdx.x * 32, r0 = blockIdx.y * 32;
  int tx = threadIdx.x, ty = threadIdx.y;   // block (32,8)
#pragma unroll
  for (int i = 0; i < 4; ++i)
    t[ty + 8 * i][tx] = in[(long)(r0 + ty + 8 * i) * C + c0 + tx];
  __syncthreads();
#pragma unroll
  for (int i = 0; i < 4; ++i)
    out[(long)(c0 + ty + 8 * i) * R + r0 + tx] = f2bf(t[tx][ty + 8 * i]);
}

// ---------------- u_s[h][d] = sum_e W[h][d][e]*a_src[h][e] ----------------
__global__ void headvec_kernel(const float* __restrict__ W, const float* __restrict__ a_s,
                               const float* __restrict__ a_d, float* __restrict__ u_s,
                               float* __restrict__ u_d) {
  int h = blockIdx.x, d = threadIdx.x;
  const float* wr = W + ((long)h * D_ + d) * D_;
  const float* as = a_s + h * D_;
  const float* ad = a_d + h * D_;
  float s = 0.f, t = 0.f;
#pragma unroll 8
  for (int e = 0; e < D_; ++e) { s += wr[e] * as[e]; t += wr[e] * ad[e]; }
  u_s[h * D_ + d] = s;
  u_d[h * D_ + d] = t;
}

// ---------------- f_s/f_d (pre-scaled by log2e and 0.2*log2e) ----------------
__global__ __launch_bounds__(256) void fvec_kernel(const float* __restrict__ x,
                                                   const float* __restrict__ u_s,
                                                   const float* __restrict__ u_d,
                                                   float* __restrict__ fsA, float* __restrict__ fsB,
                                                   float* __restrict__ fdA, float* __restrict__ fdB,
                                                   int n) {
  __shared__ float usl[128], udl[128];
  long idx = (long)blockIdx.x * 256 + threadIdx.x;
  int h = (int)(idx / n), i = (int)(idx % n);
  if (threadIdx.x < 128) {
    usl[threadIdx.x] = u_s[h * D_ + threadIdx.x];
    udl[threadIdx.x] = u_d[h * D_ + threadIdx.x];
  }
  __syncthreads();
  const float4* xr = (const float4*)(x + (long)i * D_);
  float s = 0.f, t = 0.f;
#pragma unroll 8
  for (int e4 = 0; e4 < 32; ++e4) {
    float4 xv = xr[e4];
    s += xv.x * usl[4 * e4] + xv.y * usl[4 * e4 + 1] + xv.z * usl[4 * e4 + 2] + xv.w * usl[4 * e4 + 3];
    t += xv.x * udl[4 * e4] + xv.y * udl[4 * e4 + 1] + xv.z * udl[4 * e4 + 2] + xv.w * udl[4 * e4 + 3];
  }
  const float L2E = 1.4426950408889634f;
  fsA[idx] = s * L2E; fsB[idx] = 0.2f * s * L2E;
  fdA[idx] = t * L2E; fdB[idx] = 0.2f * t * L2E;
}

// ---------------- generic bf16 MFMA GEMM: C[M][128cols] = A[M][K] * BT[ncol][K]^T ----
// block: 256 thr (4 waves), tile 64 rows x 128 cols, K in steps of 32.
// double-buffered LDS, register prefetch 1 tile ahead, one barrier per K-step.
// epi: 0 = bf16 store (WhT), 1 = fp32 relu+bias, 2 = bf16 relu+bias transposed store, 3 = fp32 plain
__global__ __launch_bounds__(256) void gemm_kernel(const short* __restrict__ A,
                                                   const short* __restrict__ BT,
                                                   int M, int K, int lda, int ldb,
                                                   float* __restrict__ outF, short* __restrict__ outB,
                                                   const float* __restrict__ bias,
                                                   int ldo, int epi,
                                                   long sA, long sBT, long sOut) {
  int bz = blockIdx.z;
  A += bz * sA;
  BT += bz * sBT;
  __shared__ __align__(16) short bs[2][4096];
  int tid = threadIdx.x, w = tid >> 6, l = tid & 63, lm = l & 15, lg = l >> 4;
  int row0 = blockIdx.x * 64 + w * 16;
  int col0 = blockIdx.y * 128;
  const short* arow = A + (long)(row0 + lm) * lda + 8 * lg;
  const short* b0 = BT + (long)(col0 + 16 * (2 * w + 0) + lm) * ldb + 8 * lg;
  const short* b1 = BT + (long)(col0 + 16 * (2 * w + 1) + lm) * ldb + 8 * lg;
  f32x4 acc[8] = {};
  int nt = K / 32;
  int4 r0 = *(const int4*)(b0);
  int4 r1 = *(const int4*)(b1);
  s16x8 af = *(const s16x8*)(arow);
  for (int kt = 0; kt < nt; ++kt) {
    ((int4*)bs[kt & 1])[(2 * w + 0) * 64 + l] = r0;
    ((int4*)bs[kt & 1])[(2 * w + 1) * 64 + l] = r1;
    int kb = (kt + 1 < nt) ? (kt + 1) * 32 : kt * 32;
    r0 = *(const int4*)(b0 + kb);
    r1 = *(const int4*)(b1 + kb);
    s16x8 an = *(const s16x8*)(arow + kb);
    __syncthreads();
#pragma unroll
    for (int f = 0; f < 8; ++f) {
      s16x8 bf = *(const s16x8*)(bs[kt & 1] + f * 512 + l * 8);
      acc[f] = __builtin_amdgcn_mfma_f32_16x16x32_bf16(af, bf, acc[f], 0, 0, 0);
    }
    af = an;
  }
#pragma unroll
  for (int f = 0; f < 8; ++f) {
    int col = col0 + 16 * f + lm;
#pragma unroll
    for (int r = 0; r < 4; ++r) {
      int row = row0 + 4 * lg + r;
      float v = acc[f][r];
      if (epi == 0) {
        outB[bz * sOut + (long)row * ldo + col] = f2bf(v);
      } else if (epi == 1) {
        v += bias[col]; v = v > 0.f ? v : 0.f;
        outF[(long)row * ldo + col] = v;
      } else if (epi == 2) {
        v += bias[col]; v = v > 0.f ? v : 0.f;
        outB[(long)col * ldo + row] = f2bf(v);
      } else {
        outF[(long)row * ldo + col] = v;
      }
    }
  }
}

// ---------------- fused masked-softmax attention, k-split partial ----------------
// grid (n/64, H, S), block 256. Writes fp32 partial acc [h][rb][s][64][128] and partial Z.
__global__ __launch_bounds__(256) void attn_kernel(const short* __restrict__ WhT,
                                                   const unsigned char* __restrict__ bits,
                                                   const float* __restrict__ fsA,
                                                   const float* __restrict__ fsB,
                                                   const float* __restrict__ fdA,
                                                   const float* __restrict__ fdB,
                                                   float* __restrict__ pacc,
                                                   float* __restrict__ pz,
                                                   int n, int S) {
  int h = blockIdx.y, sp = blockIdx.z;
  int RB = gridDim.x;
  int klen = n / S;
  int k0 = sp * klen;
  const short* whT = WhT + (long)h * D_ * n;
  const float* fa = fdA + (long)h * n;
  const float* fb = fdB + (long)h * n;
  __shared__ __align__(16) short bs[2][4096];
  int tid = threadIdx.x, w = tid >> 6, l = tid & 63, lm = l & 15, lg = l >> 4;
  int i0 = blockIdx.x * 64;
  int irow = i0 + w * 16 + lm;
  float fsAi = fsA[(long)h * n + irow];
  float fsBi = fsB[(long)h * n + irow];
  const unsigned char* brow = bits + (long)irow * (n >> 3);
  const short* s0 = whT + (long)(16 * (2 * w + 0) + lm) * n + 8 * lg + k0;
  const short* s1 = whT + (long)(16 * (2 * w + 1) + lm) * n + 8 * lg + k0;
  f32x4 acc[8] = {};
  float zacc = 0.f;
  int nt = klen / 32;
  int4 r0 = *(const int4*)(s0);
  int4 r1 = *(const int4*)(s1);
  for (int kt = 0; kt < nt; ++kt) {
    int jb = k0 + kt * 32;
    // stage current tile into LDS buffer kt&1
    ((int4*)bs[kt & 1])[(2 * w + 0) * 64 + l] = r0;
    ((int4*)bs[kt & 1])[(2 * w + 1) * 64 + l] = r1;
    // prefetch next tile
    int koff = (kt + 1 < nt) ? (kt + 1) * 32 : kt * 32;
    r0 = *(const int4*)(s0 + koff);
    r1 = *(const int4*)(s1 + koff);
    // P fragment (A operand): row lm, k = jb + 8*lg + j
    float fav[8], fbv[8];
    *(float4*)(fav) = *(const float4*)(fa + jb + 8 * lg);
    *(float4*)(fav + 4) = *(const float4*)(fa + jb + 8 * lg + 4);
    *(float4*)(fbv) = *(const float4*)(fb + jb + 8 * lg);
    *(float4*)(fbv + 4) = *(const float4*)(fb + jb + 8 * lg + 4);
    unsigned mb = brow[(jb + 8 * lg) >> 3];
    s16x8 af;
    float zs = 0.f;
#pragma unroll
    for (int j = 0; j < 8; ++j) {
      float p = exp2f(fmaxf(fsAi + fav[j], fsBi + fbv[j]));
      p = ((mb >> j) & 1u) ? p : 0.f;
      zs += p;
      af[j] = f2bf(p);
    }
    zacc += zs;
    __syncthreads();
#pragma unroll
    for (int f = 0; f < 8; ++f) {
      s16x8 bf = *(const s16x8*)(bs[kt & 1] + f * 512 + l * 8);
      acc[f] = __builtin_amdgcn_mfma_f32_16x16x32_bf16(af, bf, acc[f], 0, 0, 0);
    }
  }
  // reduce partial Z across the 4 k-groups (lanes sharing lm)
  zacc += __shfl_xor(zacc, 16);
  zacc += __shfl_xor(zacc, 32);
  long pzb = (((long)h * RB + blockIdx.x) * S + sp) * 64;
  if (l < 16) pz[pzb + w * 16 + lm] = zacc;
  long pb = (((long)h * RB + blockIdx.x) * S + sp) * 8192;
#pragma unroll
  for (int f = 0; f < 8; ++f) {
#pragma unroll
    for (int r = 0; r < 4; ++r) {
      pacc[pb + (long)(w * 16 + 4 * lg + r) * 128 + 16 * f + lm] = acc[f][r];
    }
  }
}

// ---------------- combine k-split partials: /Z, elu, write bf16 head-concat ----------------
__global__ __launch_bounds__(256) void attn_combine_kernel(const float* __restrict__ pacc,
                                                           const float* __restrict__ pz,
                                                           short* __restrict__ hcat,
                                                           int n, int S) {
  int h = blockIdx.y, rb = blockIdx.x;
  int RB = gridDim.x;
  long pb = ((long)h * RB + rb) * S * 8192;
  long zb = ((long)h * RB + rb) * S * 64;
  __shared__ float zl[64];
  int tid = threadIdx.x;
  if (tid < 64) {
    float z = 0.f;
    for (int s = 0; s < S; ++s) z += pz[zb + (long)s * 64 + tid];
    zl[tid] = 1.f / z;
  }
  __syncthreads();
  int i0 = rb * 64;
#pragma unroll
  for (int k = 0; k < 8; ++k) {
    int e = tid * 4 + k * 1024;
    int row = e >> 7, col = e & 127;
    f32x4 v = {};
    for (int s = 0; s < S; ++s) v += *(const f32x4*)(pacc + pb + (long)s * 8192 + e);
    float iz = zl[row];
    short4 o;
    float t;
    t = v[0] * iz; o.x = f2bf(t > 0.f ? t : __expf(t) - 1.f);
    t = v[1] * iz; o.y = f2bf(t > 0.f ? t : __expf(t) - 1.f);
    t = v[2] * iz; o.z = f2bf(t > 0.f ? t : __expf(t) - 1.f);
    t = v[3] * iz; o.w = f2bf(t > 0.f ? t : __expf(t) - 1.f);
    *(short4*)(hcat + (long)(i0 + row) * HD_ + h * D_ + col) = o;
  }
}

// ---------------- gated fusion + final GEMM + relu ----------------
__global__ __launch_bounds__(256) void fusion_kernel(const float* __restrict__ concept,
                                                     const float* __restrict__ ctext,
                                                     const short* __restrict__ fusT,
                                                     const float* __restrict__ fus_b,
                                                     float* __restrict__ out) {
  __shared__ __align__(16) short als[64 * 136];  // row pitch 136 shorts (272B) to dodge conflicts
  int tid = threadIdx.x;
  int r0 = blockIdx.x * 64;
#pragma unroll
  for (int it = 0; it < 8; ++it) {
    int e = it * 1024 + tid * 4;
    int r = e >> 7, c = e & 127;
    float4 cv = *(const float4*)(concept + (long)(r0 + r) * D_ + c);
    float4 tv = *(const float4*)(ctext + (long)(r0 + r) * D_ + c);
    short4 o;
    {
      float s = cv.x + tv.x; float z = 1.f / (1.f + __expf(-s)); o.x = f2bf(tv.x + z * (cv.x - tv.x));
      s = cv.y + tv.y; z = 1.f / (1.f + __expf(-s)); o.y = f2bf(tv.y + z * (cv.y - tv.y));
      s = cv.z + tv.z; z = 1.f / (1.f + __expf(-s)); o.z = f2bf(tv.z + z * (cv.z - tv.z));
      s = cv.w + tv.w; z = 1.f / (1.f + __expf(-s)); o.w = f2bf(tv.w + z * (cv.w - tv.w));
    }
    *(short4*)(als + (long)r * 136 + c) = o;
  }
  __syncthreads();
  int w = tid >> 6, l = tid & 63, lm = l & 15, lg = l >> 4;
  f32x4 acc[8] = {};
#pragma unroll
  for (int kt = 0; kt < 4; ++kt) {
    int kb = kt * 32;
    s16x8 af = *(const s16x8*)(als + (16 * w + lm) * 136 + kb + 8 * lg);
#pragma unroll
    for (int f = 0; f < 8; ++f) {
      s16x8 bf = *(const s16x8*)(fusT + (long)(16 * f + lm) * D_ + kb + 8 * lg);
      acc[f] = __builtin_amdgcn_mfma_f32_16x16x32_bf16(af, bf, acc[f], 0, 0, 0);
    }
  }
#pragma unroll
  for (int f = 0; f < 8; ++f) {
    int col = 16 * f + lm;
#pragma unroll
    for (int r = 0; r < 4; ++r) {
      float v = acc[f][r] + fus_b[col];
      v = v > 0.f ? v : 0.f;
      out[(long)(r0 + 16 * w + 4 * lg + r) * D_ + col] = v;
    }
  }
}

extern "C" void kernel_launch(void* const* d_in, const int* in_sizes, int n_in,
                              void* d_out, int out_size, void* d_ws, size_t ws_size,
                              hipStream_t stream) {
  (void)in_sizes; (void)n_in; (void)out_size;
  const float* x      = (const float*)d_in[0];
  const int*   adj    = (const int*)d_in[1];
  const float* t_x    = (const float*)d_in[2];
  const int*   t_adj  = (const int*)d_in[3];
  const float* tfidf  = (const float*)d_in[4];
  const float* Wg     = (const float*)d_in[5];
  const float* ag_src = (const float*)d_in[6];
  const float* ag_dst = (const float*)d_in[7];
  const float* fcg_W  = (const float*)d_in[8];
  const float* fcg_b  = (const float*)d_in[9];
  const float* Wt     = (const float*)d_in[10];
  const float* at_src = (const float*)d_in[11];
  const float* at_dst = (const float*)d_in[12];
  const float* fct_W  = (const float*)d_in[13];
  const float* fct_b  = (const float*)d_in[14];
  const float* fus_W  = (const float*)d_in[15];
  const float* fus_b  = (const float*)d_in[16];
  float* out = (float*)d_out;

  char* ws = (char*)d_ws;
  size_t off = 0;
  auto alloc = [&](size_t bytes) -> char* {
    char* p = ws + off;
    off = (off + bytes + 255) & ~(size_t)255;
    return p;
  };
  unsigned long long* bitsG = (unsigned long long*)alloc((size_t)N_ * N_ / 8);
  unsigned long long* bitsT = (unsigned long long*)alloc((size_t)T_ * T_ / 8);
  short* xb     = (short*)alloc((size_t)N_ * D_ * 2);
  short* txb    = (short*)alloc((size_t)T_ * D_ * 2);
  short* WgT    = (short*)alloc((size_t)H_ * D_ * D_ * 2);
  short* WtT    = (short*)alloc((size_t)H_ * D_ * D_ * 2);
  short* fcgT   = (short*)alloc((size_t)HD_ * D_ * 2);
  short* fctT   = (short*)alloc((size_t)HD_ * D_ * 2);
  short* fusT   = (short*)alloc((size_t)D_ * D_ * 2);
  short* tfidfT = (short*)alloc((size_t)N_ * T_ * 2);
  short* WhTg   = (short*)alloc((size_t)H_ * D_ * N_ * 2);
  short* WhTt   = (short*)alloc((size_t)H_ * D_ * T_ * 2);
  float* usG = (float*)alloc(H_ * D_ * 4);
  float* udG = (float*)alloc(H_ * D_ * 4);
  float* usT = (float*)alloc(H_ * D_ * 4);
  float* udT = (float*)alloc(H_ * D_ * 4);
  float* fsAg = (float*)alloc((size_t)H_ * N_ * 4);
  float* fsBg = (float*)alloc((size_t)H_ * N_ * 4);
  float* fdAg = (float*)alloc((size_t)H_ * N_ * 4);
  float* fdBg = (float*)alloc((size_t)H_ * N_ * 4);
  float* fsAt = (float*)alloc((size_t)H_ * T_ * 4);
  float* fsBt = (float*)alloc((size_t)H_ * T_ * 4);
  float* fdAt = (float*)alloc((size_t)H_ * T_ * 4);
  float* fdBt = (float*)alloc((size_t)H_ * T_ * 4);
  short* hcatG = (short*)alloc((size_t)N_ * HD_ * 2);
  short* hcatT = (short*)alloc((size_t)T_ * HD_ * 2);
  short* gatT  = (short*)alloc((size_t)D_ * T_ * 2);
  float* conceptF = (float*)alloc((size_t)N_ * D_ * 4);
  float* ctextF   = (float*)alloc((size_t)N_ * D_ * 4);

  // k-split partials, sized to fit remaining workspace
  const int RBg = N_ / 64, RBt = T_ / 64;
  const size_t paccG1 = (size_t)H_ * RBg * 8192 * 4, pzG1 = (size_t)H_ * RBg * 64 * 4;
  const size_t paccT1 = (size_t)H_ * RBt * 8192 * 4, pzT1 = (size_t)H_ * RBt * 64 * 4;
  size_t rem = (ws_size > off + (1 << 20)) ? (ws_size - off - (1 << 20)) : 0;
  int Sg = 1, St = 1;
  if (rem >= 4 * (paccG1 + pzG1) + 4 * (paccT1 + pzT1)) { Sg = 4; St = 4; }
  else if (rem >= 2 * (paccG1 + pzG1) + 4 * (paccT1 + pzT1)) { Sg = 2; St = 4; }
  else if (rem >= 2 * (paccG1 + pzG1) + 2 * (paccT1 + pzT1)) { Sg = 2; St = 2; }
  else if (rem >= 1 * (paccG1 + pzG1) + 2 * (paccT1 + pzT1)) { Sg = 1; St = 2; }
  float* paccG = (float*)alloc(Sg * paccG1);
  float* pzG   = (float*)alloc(Sg * pzG1);
  float* paccT = (float*)alloc(St * paccT1);
  float* pzT   = (float*)alloc(St * pzT1);

  // --- prep ---
  bits_kernel<<<dim3(1024), dim3(256), 0, stream>>>(adj, bitsG, N_ * N_ / 64);
  bits_kernel<<<dim3(512), dim3(256), 0, stream>>>(t_adj, bitsT, T_ * T_ / 64);
  cvt_kernel<<<dim3(N_ * D_ / 1024), dim3(256), 0, stream>>>(x, xb, N_ * D_ / 4);
  cvt_kernel<<<dim3(T_ * D_ / 1024), dim3(256), 0, stream>>>(t_x, txb, T_ * D_ / 4);
  tcvt_kernel<<<dim3(4, 4, 4), dim3(32, 8), 0, stream>>>(Wg, WgT, D_, D_, (long)D_ * D_, (long)D_ * D_);
  tcvt_kernel<<<dim3(4, 4, 4), dim3(32, 8), 0, stream>>>(Wt, WtT, D_, D_, (long)D_ * D_, (long)D_ * D_);
  tcvt_kernel<<<dim3(4, 16, 1), dim3(32, 8), 0, stream>>>(fcg_W, fcgT, HD_, D_, 0, 0);
  tcvt_kernel<<<dim3(4, 16, 1), dim3(32, 8), 0, stream>>>(fct_W, fctT, HD_, D_, 0, 0);
  tcvt_kernel<<<dim3(4, 4, 1), dim3(32, 8), 0, stream>>>(fus_W, fusT, D_, D_, 0, 0);
  tcvt_kernel<<<dim3(N_ / 32, T_ / 32, 1), dim3(32, 8), 0, stream>>>(tfidf, tfidfT, T_, N_, 0, 0);
  headvec_kernel<<<dim3(H_), dim3(128), 0, stream>>>(Wg, ag_src, ag_dst, usG, udG);
  headvec_kernel<<<dim3(H_), dim3(128), 0, stream>>>(Wt, at_src, at_dst, usT, udT);
  fvec_kernel<<<dim3(H_ * N_ / 256), dim3(256), 0, stream>>>(x, usG, udG, fsAg, fsBg, fdAg, fdBg, N_);
  fvec_kernel<<<dim3(H_ * T_ / 256), dim3(256), 0, stream>>>(t_x, usT, udT, fsAt, fsBt, fdAt, fdBt, T_);

  // --- WhT = W^T x^T  (per head), bf16 out [H][128][n] ---
  gemm_kernel<<<dim3(2, N_ / 128, H_), dim3(256), 0, stream>>>(
      WgT, xb, D_, D_, D_, D_, nullptr, WhTg, nullptr, N_, 0,
      (long)D_ * D_, 0, (long)D_ * N_);
  gemm_kernel<<<dim3(2, T_ / 128, H_), dim3(256), 0, stream>>>(
      WtT, txb, D_, D_, D_, D_, nullptr, WhTt, nullptr, T_, 0,
      (long)D_ * D_, 0, (long)D_ * T_);

  // --- attention (k-split partials + combine) ---
  attn_kernel<<<dim3(RBg, H_, Sg), dim3(256), 0, stream>>>(
      WhTg, (const unsigned char*)bitsG, fsAg, fsBg, fdAg, fdBg, paccG, pzG, N_, Sg);
  attn_combine_kernel<<<dim3(RBg, H_), dim3(256), 0, stream>>>(paccG, pzG, hcatG, N_, Sg);
  attn_kernel<<<dim3(RBt, H_, St), dim3(256), 0, stream>>>(
      WhTt, (const unsigned char*)bitsT, fsAt, fsBt, fdAt, fdBt, paccT, pzT, T_, St);
  attn_combine_kernel<<<dim3(RBt, H_), dim3(256), 0, stream>>>(paccT, pzT, hcatT, T_, St);

  // --- head-concat FC: concept (fp32) and gat_text (bf16, transposed) ---
  gemm_kernel<<<dim3(N_ / 64, 1, 1), dim3(256), 0, stream>>>(
      hcatG, fcgT, N_, HD_, HD_, HD_, conceptF, nullptr, fcg_b, D_, 1, 0, 0, 0);
  gemm_kernel<<<dim3(T_ / 64, 1, 1), dim3(256), 0, stream>>>(
      hcatT, fctT, T_, HD_, HD_, HD_, nullptr, gatT, fct_b, T_, 2, 0, 0, 0);

  // --- c_text = tfidf^T @ gat_text ---
  gemm_kernel<<<dim3(N_ / 64, 1, 1), dim3(256), 0, stream>>>(
      tfidfT, gatT, N_, T_, T_, T_, ctextF, nullptr, nullptr, D_, 3, 0, 0, 0);

  // --- gated fusion + final linear + relu ---
  fusion_kernel<<<dim3(N_ / 64), dim3(256), 0, stream>>>(conceptF, ctextF, fusT, fus_b, out);
}